// Round 1
// baseline (977.809 us; speedup 1.0000x reference)
//
#include <hip/hip_runtime.h>
#include <hip/hip_bf16.h>
#include <math.h>

#define B_   32
#define T_   4096
#define D_   1024
#define H_   256
#define KTH  2048           // threshold_index = int(T*0.5)
#define NC   16             // t-chunks for phase 3
#define TC   (T_/NC)        // 256

// ---------- helpers ----------
__device__ inline unsigned f2s(float f) {
    unsigned u = __float_as_uint(f);
    return (u & 0x80000000u) ? ~u : (u | 0x80000000u);
}
__device__ inline float s2f(unsigned s) {
    unsigned x = (s & 0x80000000u) ? (s & 0x7fffffffu) : ~s;
    return __uint_as_float(x);
}

__device__ inline int block_sum_i(int v, int* sb, int tid) {
    #pragma unroll
    for (int o = 32; o; o >>= 1) v += __shfl_down(v, o);
    __syncthreads();
    if ((tid & 63) == 0) sb[tid >> 6] = v;
    __syncthreads();
    return sb[0] + sb[1] + sb[2] + sb[3];
}
__device__ inline float block_max_f(float v, float* sb, int tid) {
    #pragma unroll
    for (int o = 32; o; o >>= 1) v = fmaxf(v, __shfl_down(v, o));
    __syncthreads();
    if ((tid & 63) == 0) sb[tid >> 6] = v;
    __syncthreads();
    return fmaxf(fmaxf(sb[0], sb[1]), fmaxf(sb[2], sb[3]));
}
__device__ inline float block_sum_f(float v, float* sb, int tid) {
    #pragma unroll
    for (int o = 32; o; o >>= 1) v += __shfl_down(v, o);
    __syncthreads();
    if ((tid & 63) == 0) sb[tid >> 6] = v;
    __syncthreads();
    return sb[0] + sb[1] + sb[2] + sb[3];
}

// ---------- phase 1: e[row] = b2 + sum_h tanh(x[row]·W1[:,h] + b1[h]) * W2[h] ----------
// GEMM M=B*T, N=256, K=1024.  Block: 64 rows x 256 h, BK=16.  256 threads,
// thread (ty=tid/32, tx=tid%32) computes 8 rows x 8 h register tile.
__global__ __launch_bounds__(256) void k_e(const float* __restrict__ x,
                                           const float* __restrict__ W1,
                                           const float* __restrict__ b1,
                                           const float* __restrict__ W2,
                                           const float* __restrict__ b2,
                                           float* __restrict__ e_out) {
    __shared__ float sA[16][64];    // [k][m]
    __shared__ float sB[16][256];   // [k][n]
    __shared__ float red[64][33];   // padded reduce buffer

    const int tid = threadIdx.x;
    const int tx = tid & 31;
    const int ty = tid >> 5;
    const long row0 = (long)blockIdx.x * 64;

    float acc[8][8];
    #pragma unroll
    for (int i = 0; i < 8; i++)
        #pragma unroll
        for (int j = 0; j < 8; j++) acc[i][j] = 0.f;

    for (int k0 = 0; k0 < D_; k0 += 16) {
        __syncthreads();
        // A tile: 64 rows x 16 k
        {
            int r  = tid >> 2;
            int kk = (tid & 3) << 2;
            const float4 v = *reinterpret_cast<const float4*>(&x[(row0 + r) * D_ + k0 + kk]);
            sA[kk + 0][r] = v.x; sA[kk + 1][r] = v.y;
            sA[kk + 2][r] = v.z; sA[kk + 3][r] = v.w;
        }
        // B tile: 16 k x 256 n
        #pragma unroll
        for (int i = 0; i < 4; i++) {
            int idx = tid + i * 256;          // float4 index, 1024 total
            int kk = idx >> 6;
            int n  = (idx & 63) << 2;
            *reinterpret_cast<float4*>(&sB[kk][n]) =
                *reinterpret_cast<const float4*>(&W1[(long)(k0 + kk) * H_ + n]);
        }
        __syncthreads();
        #pragma unroll
        for (int k = 0; k < 16; k++) {
            float a[8], bb[8];
            *(float4*)&a[0]  = *(float4*)&sA[k][ty * 8];
            *(float4*)&a[4]  = *(float4*)&sA[k][ty * 8 + 4];
            *(float4*)&bb[0] = *(float4*)&sB[k][tx * 8];
            *(float4*)&bb[4] = *(float4*)&sB[k][tx * 8 + 4];
            #pragma unroll
            for (int i = 0; i < 8; i++)
                #pragma unroll
                for (int j = 0; j < 8; j++)
                    acc[i][j] = fmaf(a[i], bb[j], acc[i][j]);
        }
    }

    // epilogue: tanh + dot with W2, reduce across the 32 n-groups
    const int h0 = tx * 8;
    float w2v[8], b1v[8];
    #pragma unroll
    for (int j = 0; j < 8; j++) { w2v[j] = W2[h0 + j]; b1v[j] = b1[h0 + j]; }

    float pe[8];
    #pragma unroll
    for (int i = 0; i < 8; i++) {
        float s = 0.f;
        #pragma unroll
        for (int j = 0; j < 8; j++)
            s += tanhf(acc[i][j] + b1v[j]) * w2v[j];
        pe[i] = s;
    }
    __syncthreads();
    #pragma unroll
    for (int i = 0; i < 8; i++) red[ty * 8 + i][tx] = pe[i];
    __syncthreads();
    if (tid < 64) {
        float s = 0.f;
        #pragma unroll
        for (int j = 0; j < 32; j++) s += red[tid][j];
        e_out[row0 + tid] = s + b2[0];
    }
}

// ---------- phase 2: per batch, exact rank-KTH threshold + masked softmax weights ----------
__global__ __launch_bounds__(256) void k_thresh(const float* __restrict__ e,
                                                float* __restrict__ beta) {
    __shared__ int   sbi[4];
    __shared__ float sbf[4];
    const int b = blockIdx.x, tid = threadIdx.x;
    const float* eb = e + (long)b * T_;

    float    fe[16];
    unsigned ue[16];
    #pragma unroll
    for (int i = 0; i < 16; i++) {
        fe[i] = eb[tid + i * 256];
        ue[i] = f2s(fe[i]);
    }

    // smallest v with count(u <= v) >= KTH+1  -> 0-indexed KTH-th order statistic
    unsigned lo = 0u, hi = 0xFFFFFFFFu;
    while (lo < hi) {
        unsigned mid = lo + ((hi - lo) >> 1);
        int c = 0;
        #pragma unroll
        for (int i = 0; i < 16; i++) c += (ue[i] <= mid) ? 1 : 0;
        int total = block_sum_i(c, sbi, tid);
        if (total >= KTH + 1) hi = mid; else lo = mid + 1;
    }
    const float thr = s2f(lo);

    // survivors: e < thr  (reference masks e >= thr with -1e8; +1.0 shift cancels in softmax)
    float m = -INFINITY;
    #pragma unroll
    for (int i = 0; i < 16; i++) if (fe[i] < thr) m = fmaxf(m, fe[i]);
    m = block_max_f(m, sbf, tid);

    float s = 0.f;
    #pragma unroll
    for (int i = 0; i < 16; i++) if (fe[i] < thr) s += expf(fe[i] - m);
    s = block_sum_f(s, sbf, tid);
    const float inv = 1.0f / s;

    #pragma unroll
    for (int i = 0; i < 16; i++) {
        float w = (fe[i] < thr) ? expf(fe[i] - m) * inv : 0.0f;
        beta[(long)b * T_ + tid + i * 256] = w;
    }
}

// ---------- phase 3: partial[b][c][d] = sum_{t in chunk c} beta[b,t] * x[b,t,d] ----------
__global__ __launch_bounds__(256) void k_pv(const float* __restrict__ x,
                                            const float* __restrict__ beta,
                                            float* __restrict__ partial) {
    const int c = blockIdx.x;
    const int b = blockIdx.y;
    const int tid = threadIdx.x;
    __shared__ float sBeta[TC];
    sBeta[tid] = beta[(long)b * T_ + c * TC + tid];
    __syncthreads();

    float4 acc = {0.f, 0.f, 0.f, 0.f};
    const float* xb = x + ((long)b * T_ + (long)c * TC) * D_ + tid * 4;
    for (int t = 0; t < TC; t++) {
        float w = sBeta[t];
        if (w != 0.0f) {                       // uniform branch: skip masked rows
            float4 v = *reinterpret_cast<const float4*>(xb + (long)t * D_);
            acc.x = fmaf(w, v.x, acc.x);
            acc.y = fmaf(w, v.y, acc.y);
            acc.z = fmaf(w, v.z, acc.z);
            acc.w = fmaf(w, v.w, acc.w);
        }
    }
    *reinterpret_cast<float4*>(&partial[(((long)b * NC) + c) * D_ + tid * 4]) = acc;
}

// ---------- phase 4: out[b][d] = sum_c partial[b][c][d] ----------
__global__ __launch_bounds__(256) void k_red(const float* __restrict__ partial,
                                             float* __restrict__ out) {
    const int b = blockIdx.x, tid = threadIdx.x;
    float4 acc = {0.f, 0.f, 0.f, 0.f};
    #pragma unroll
    for (int c = 0; c < NC; c++) {
        float4 v = *reinterpret_cast<const float4*>(&partial[(((long)b * NC) + c) * D_ + tid * 4]);
        acc.x += v.x; acc.y += v.y; acc.z += v.z; acc.w += v.w;
    }
    *reinterpret_cast<float4*>(&out[(long)b * D_ + tid * 4]) = acc;
}

extern "C" void kernel_launch(void* const* d_in, const int* in_sizes, int n_in,
                              void* d_out, int out_size, void* d_ws, size_t ws_size,
                              hipStream_t stream) {
    const float* x  = (const float*)d_in[0];
    const float* W1 = (const float*)d_in[1];
    const float* b1 = (const float*)d_in[2];
    const float* W2 = (const float*)d_in[3];
    const float* b2 = (const float*)d_in[4];
    float* out = (float*)d_out;

    float* e       = (float*)d_ws;                 // B*T
    float* beta    = e + (size_t)B_ * T_;          // B*T
    float* partial = beta + (size_t)B_ * T_;       // B*NC*D

    k_e<<<(B_ * T_) / 64, 256, 0, stream>>>(x, W1, b1, W2, b2, e);
    k_thresh<<<B_, 256, 0, stream>>>(e, beta);
    k_pv<<<dim3(NC, B_), 256, 0, stream>>>(x, beta, partial);
    k_red<<<B_, 256, 0, stream>>>(partial, out);
}

// Round 2
// 418.154 us; speedup vs baseline: 2.3384x; 2.3384x over previous
//
#include <hip/hip_runtime.h>
#include <hip/hip_bf16.h>
#include <math.h>

#define B_   32
#define T_   4096
#define D_   1024
#define H_   256
#define KTH  2048           // threshold_index = int(T*0.5)
#define NC   16
#define TC   (T_/NC)
#define BM   128
#define BK   32
#define EPSB 2.0e-3f        // refinement band half-width (e-error ~6e-5)
#define MAXBAND 256

typedef __attribute__((ext_vector_type(8))) short short8;
typedef __attribute__((ext_vector_type(4))) float f32x4;

// ---------- helpers ----------
__device__ inline unsigned f2s(float f) {
    unsigned u = __float_as_uint(f);
    return (u & 0x80000000u) ? ~u : (u | 0x80000000u);
}
__device__ inline float s2f(unsigned s) {
    unsigned x = (s & 0x80000000u) ? (s & 0x7fffffffu) : ~s;
    return __uint_as_float(x);
}
__device__ inline int block_sum_i(int v, int* sb, int tid) {
    #pragma unroll
    for (int o = 32; o; o >>= 1) v += __shfl_down(v, o);
    __syncthreads();
    if ((tid & 63) == 0) sb[tid >> 6] = v;
    __syncthreads();
    return sb[0] + sb[1] + sb[2] + sb[3];
}
__device__ inline float block_max_f(float v, float* sb, int tid) {
    #pragma unroll
    for (int o = 32; o; o >>= 1) v = fmaxf(v, __shfl_down(v, o));
    __syncthreads();
    if ((tid & 63) == 0) sb[tid >> 6] = v;
    __syncthreads();
    return fmaxf(fmaxf(sb[0], sb[1]), fmaxf(sb[2], sb[3]));
}
__device__ inline float block_sum_f(float v, float* sb, int tid) {
    #pragma unroll
    for (int o = 32; o; o >>= 1) v += __shfl_down(v, o);
    __syncthreads();
    if ((tid & 63) == 0) sb[tid >> 6] = v;
    __syncthreads();
    return sb[0] + sb[1] + sb[2] + sb[3];
}

// split fp32 -> bf16 hi/lo (truncation), pack 8 floats -> 2x uint4 (8 bf16 each)
__device__ inline void cvt8(const float4 va, const float4 vb, uint4& h, uint4& l) {
    float f[8] = {va.x, va.y, va.z, va.w, vb.x, vb.y, vb.z, vb.w};
    unsigned hu[8], lu[8];
    #pragma unroll
    for (int i = 0; i < 8; i++) {
        unsigned u = __float_as_uint(f[i]);
        hu[i] = u & 0xFFFF0000u;
        lu[i] = __float_as_uint(f[i] - __uint_as_float(hu[i])) & 0xFFFF0000u;
    }
    h = make_uint4((hu[0]>>16)|hu[1], (hu[2]>>16)|hu[3], (hu[4]>>16)|hu[5], (hu[6]>>16)|hu[7]);
    l = make_uint4((lu[0]>>16)|lu[1], (lu[2]>>16)|lu[3], (lu[4]>>16)|lu[5], (lu[6]>>16)|lu[7]);
}

// ---------- W1 [K][N] fp32 -> W1T hi/lo bf16 [N][K] ----------
__global__ __launch_bounds__(256) void k_w1t(const float* __restrict__ W1,
                                             ushort* __restrict__ Whi,
                                             ushort* __restrict__ Wlo) {
    __shared__ float tile[32][33];
    const int kb = blockIdx.x * 32, nb = blockIdx.y * 32;
    const int tx = threadIdx.x & 31, ty = threadIdx.x >> 5;   // ty 0..7
    #pragma unroll
    for (int i = 0; i < 4; i++)
        tile[ty + 8*i][tx] = W1[(long)(kb + ty + 8*i) * H_ + nb + tx];
    __syncthreads();
    #pragma unroll
    for (int i = 0; i < 4; i++) {
        float f = tile[tx][ty + 8*i];
        unsigned u = __float_as_uint(f);
        unsigned hi = u & 0xFFFF0000u;
        unsigned lo = __float_as_uint(f - __uint_as_float(hi)) & 0xFFFF0000u;
        long o = (long)(nb + ty + 8*i) * D_ + kb + tx;
        Whi[o] = (ushort)(hi >> 16);
        Wlo[o] = (ushort)(lo >> 16);
    }
}

// ---------- phase 1: MFMA GEMM (split-bf16) + tanh/W2 epilogue -> e ----------
// M=B*T rows, N=256, K=1024. 512 thr = 8 waves (2m x 4n), wave tile 64x64,
// 4x4 frags of 16x16x32. LDS tiles chunk-XOR swizzled: slot = c ^ ((row>>1)&3).
__global__ __launch_bounds__(512) void k_e_mfma(
    const float* __restrict__ x,
    const ushort* __restrict__ Whi, const ushort* __restrict__ Wlo,
    const float* __restrict__ b1, const float* __restrict__ W2,
    const float* __restrict__ b2, float* __restrict__ e_out)
{
    __shared__ ushort sAh[BM*BK], sAl[BM*BK];   // 8 KB each
    __shared__ ushort sBh[H_*BK], sBl[H_*BK];   // 16 KB each
    __shared__ float  sRed[4][BM];

    const int tid  = threadIdx.x;
    const int lane = tid & 63;
    const int wv   = tid >> 6;
    const int wm   = wv >> 2, wn = wv & 3;
    const int l15  = lane & 15, lg = lane >> 4;
    const long row0 = (long)blockIdx.x * BM;

    // A staging: thread -> row=tid>>2 (0..127), chunk=tid&3 (8 floats)
    const int ar = tid >> 2, ac = tid & 3;
    const int as = ac ^ ((ar >> 1) & 3);
    const float* ag = x + (row0 + ar) * (long)D_ + ac * 8;
    ushort* awh = &sAh[ar * BK + as * 8];
    ushort* awl = &sAl[ar * BK + as * 8];

    // B staging: thread -> n=tid>>1, slots bs0,bs0+1 (16 bf16 hi + 16 lo)
    const int bn = tid >> 1, bs0 = (tid & 1) * 2, bs1 = bs0 + 1;
    const int bx = (bn >> 1) & 3;
    const ushort* bgh0 = Whi + (long)bn * D_ + (bs0 ^ bx) * 8;
    const ushort* bgh1 = Whi + (long)bn * D_ + (bs1 ^ bx) * 8;
    const ushort* bgl0 = Wlo + (long)bn * D_ + (bs0 ^ bx) * 8;
    const ushort* bgl1 = Wlo + (long)bn * D_ + (bs1 ^ bx) * 8;
    ushort* bwh0 = &sBh[bn * BK + bs0 * 8];
    ushort* bwh1 = &sBh[bn * BK + bs1 * 8];
    ushort* bwl0 = &sBl[bn * BK + bs0 * 8];
    ushort* bwl1 = &sBl[bn * BK + bs1 * 8];

    int aoff[4], boff[4];
    #pragma unroll
    for (int fm = 0; fm < 4; fm++) {
        int r = wm * 64 + fm * 16 + l15;
        aoff[fm] = r * BK + (lg ^ ((r >> 1) & 3)) * 8;
    }
    #pragma unroll
    for (int fn = 0; fn < 4; fn++) {
        int n = wn * 64 + fn * 16 + l15;
        boff[fn] = n * BK + (lg ^ ((n >> 1) & 3)) * 8;
    }

    f32x4 acc[4][4];
    #pragma unroll
    for (int i = 0; i < 4; i++)
        #pragma unroll
        for (int j = 0; j < 4; j++) acc[i][j] = (f32x4){0.f, 0.f, 0.f, 0.f};

    for (int k0 = 0; k0 < D_; k0 += BK) {
        __syncthreads();
        float4 va = *(const float4*)(ag + k0);
        float4 vb = *(const float4*)(ag + k0 + 4);
        uint4 th0 = *(const uint4*)(bgh0 + k0);
        uint4 th1 = *(const uint4*)(bgh1 + k0);
        uint4 tl0 = *(const uint4*)(bgl0 + k0);
        uint4 tl1 = *(const uint4*)(bgl1 + k0);
        uint4 ah4, al4;
        cvt8(va, vb, ah4, al4);
        *(uint4*)awh  = ah4; *(uint4*)awl  = al4;
        *(uint4*)bwh0 = th0; *(uint4*)bwh1 = th1;
        *(uint4*)bwl0 = tl0; *(uint4*)bwl1 = tl1;
        __syncthreads();

        short8 bh[4], bl[4];
        #pragma unroll
        for (int fn = 0; fn < 4; fn++) {
            bh[fn] = *(const short8*)&sBh[boff[fn]];
            bl[fn] = *(const short8*)&sBl[boff[fn]];
        }
        #pragma unroll
        for (int fm = 0; fm < 4; fm++) {
            short8 ah = *(const short8*)&sAh[aoff[fm]];
            short8 al = *(const short8*)&sAl[aoff[fm]];
            #pragma unroll
            for (int fn = 0; fn < 4; fn++) {
                acc[fm][fn] = __builtin_amdgcn_mfma_f32_16x16x32_bf16(ah, bh[fn], acc[fm][fn], 0, 0, 0);
                acc[fm][fn] = __builtin_amdgcn_mfma_f32_16x16x32_bf16(ah, bl[fn], acc[fm][fn], 0, 0, 0);
                acc[fm][fn] = __builtin_amdgcn_mfma_f32_16x16x32_bf16(al, bh[fn], acc[fm][fn], 0, 0, 0);
            }
        }
    }

    // epilogue: e-row partial = sum_j tanh(G+b1[j])*W2[j]; D frag: col=l15, row=4*lg+r
    float b1v[4], w2v[4];
    #pragma unroll
    for (int fn = 0; fn < 4; fn++) {
        int j = wn * 64 + fn * 16 + l15;
        b1v[fn] = b1[j]; w2v[fn] = W2[j];
    }
    #pragma unroll
    for (int fm = 0; fm < 4; fm++) {
        #pragma unroll
        for (int r = 0; r < 4; r++) {
            float s = 0.f;
            #pragma unroll
            for (int fn = 0; fn < 4; fn++)
                s += tanhf(acc[fm][fn][r] + b1v[fn]) * w2v[fn];
            s += __shfl_xor(s, 1); s += __shfl_xor(s, 2);
            s += __shfl_xor(s, 4); s += __shfl_xor(s, 8);
            if (l15 == 0) sRed[wn][wm * 64 + fm * 16 + lg * 4 + r] = s;
        }
    }
    __syncthreads();
    if (tid < BM)
        e_out[row0 + tid] = sRed[0][tid] + sRed[1][tid] + sRed[2][tid] + sRed[3][tid] + b2[0];
}

// ---------- phase 2: rank threshold; BUILD=1 -> band list, BUILD=0 -> softmax ----------
template<int BUILD>
__global__ __launch_bounds__(256) void k_thresh(const float* __restrict__ e,
                                                float* __restrict__ beta,
                                                int* __restrict__ counts,
                                                int* __restrict__ list) {
    __shared__ int   sbi[4];
    __shared__ float sbf[4];
    __shared__ int   scnt;
    const int b = blockIdx.x, tid = threadIdx.x;
    const float* eb = e + (long)b * T_;

    float fe[16]; unsigned ue[16];
    #pragma unroll
    for (int i = 0; i < 16; i++) { fe[i] = eb[tid + i * 256]; ue[i] = f2s(fe[i]); }

    unsigned lo = 0u, hi = 0xFFFFFFFFu;
    while (lo < hi) {
        unsigned mid = lo + ((hi - lo) >> 1);
        int c = 0;
        #pragma unroll
        for (int i = 0; i < 16; i++) c += (ue[i] <= mid) ? 1 : 0;
        int total = block_sum_i(c, sbi, tid);
        if (total >= KTH + 1) hi = mid; else lo = mid + 1;
    }
    const float thr = s2f(lo);

    if (BUILD) {
        if (tid == 0) scnt = 0;
        __syncthreads();
        #pragma unroll
        for (int i = 0; i < 16; i++) {
            if (fabsf(fe[i] - thr) <= EPSB) {
                int p = atomicAdd(&scnt, 1);
                if (p < MAXBAND) list[b * MAXBAND + p] = tid + i * 256;
            }
        }
        __syncthreads();
        if (tid == 0) counts[b] = scnt < MAXBAND ? scnt : MAXBAND;
    } else {
        float m = -INFINITY;
        #pragma unroll
        for (int i = 0; i < 16; i++) if (fe[i] < thr) m = fmaxf(m, fe[i]);
        m = block_max_f(m, sbf, tid);
        float s = 0.f;
        #pragma unroll
        for (int i = 0; i < 16; i++) if (fe[i] < thr) s += expf(fe[i] - m);
        s = block_sum_f(s, sbf, tid);
        const float inv = 1.0f / s;
        #pragma unroll
        for (int i = 0; i < 16; i++)
            beta[(long)b * T_ + tid + i * 256] = (fe[i] < thr) ? expf(fe[i] - m) * inv : 0.0f;
    }
}

// ---------- phase 2.5: exact fp32 recompute of band rows ----------
__global__ __launch_bounds__(256) void k_refine(const float* __restrict__ x,
        const float* __restrict__ W1, const float* __restrict__ b1,
        const float* __restrict__ W2, const float* __restrict__ b2,
        const int* __restrict__ counts, const int* __restrict__ list,
        float* __restrict__ e) {
    const int b = blockIdx.y, idx = blockIdx.x;
    if (idx >= counts[b]) return;
    const int t = list[b * MAXBAND + idx];
    __shared__ float xs[D_];
    __shared__ float sbf[4];
    const int tid = threadIdx.x;
    const float* xr = x + ((long)b * T_ + t) * D_;
    *(float4*)&xs[tid * 4] = *(const float4*)&xr[tid * 4];
    __syncthreads();
    float a0 = 0.f, a1 = 0.f, a2 = 0.f, a3 = 0.f;
    for (int k = 0; k < D_; k += 4) {
        a0 = fmaf(xs[k + 0], W1[(long)(k + 0) * H_ + tid], a0);
        a1 = fmaf(xs[k + 1], W1[(long)(k + 1) * H_ + tid], a1);
        a2 = fmaf(xs[k + 2], W1[(long)(k + 2) * H_ + tid], a2);
        a3 = fmaf(xs[k + 3], W1[(long)(k + 3) * H_ + tid], a3);
    }
    float v = tanhf((a0 + a1) + (a2 + a3) + b1[tid]) * W2[tid];
    float tot = block_sum_f(v, sbf, tid);
    if (tid == 0) e[(long)b * T_ + t] = tot + b2[0];
}

// ---------- phase 3: partial[b][c][d] = sum_{t in chunk} beta*x ----------
__global__ __launch_bounds__(256) void k_pv(const float* __restrict__ x,
                                            const float* __restrict__ beta,
                                            float* __restrict__ partial) {
    const int c = blockIdx.x, b = blockIdx.y, tid = threadIdx.x;
    __shared__ float sBeta[TC];
    sBeta[tid] = beta[(long)b * T_ + c * TC + tid];
    __syncthreads();
    float4 acc = {0.f, 0.f, 0.f, 0.f};
    const float* xb = x + ((long)b * T_ + (long)c * TC) * D_ + tid * 4;
    for (int t = 0; t < TC; t++) {
        float w = sBeta[t];
        if (w != 0.0f) {
            float4 v = *reinterpret_cast<const float4*>(xb + (long)t * D_);
            acc.x = fmaf(w, v.x, acc.x);
            acc.y = fmaf(w, v.y, acc.y);
            acc.z = fmaf(w, v.z, acc.z);
            acc.w = fmaf(w, v.w, acc.w);
        }
    }
    *reinterpret_cast<float4*>(&partial[(((long)b * NC) + c) * D_ + tid * 4]) = acc;
}

// ---------- phase 4 ----------
__global__ __launch_bounds__(256) void k_red(const float* __restrict__ partial,
                                             float* __restrict__ out) {
    const int b = blockIdx.x, tid = threadIdx.x;
    float4 acc = {0.f, 0.f, 0.f, 0.f};
    #pragma unroll
    for (int c = 0; c < NC; c++) {
        float4 v = *reinterpret_cast<const float4*>(&partial[(((long)b * NC) + c) * D_ + tid * 4]);
        acc.x += v.x; acc.y += v.y; acc.z += v.z; acc.w += v.w;
    }
    *reinterpret_cast<float4*>(&out[(long)b * D_ + tid * 4]) = acc;
}

extern "C" void kernel_launch(void* const* d_in, const int* in_sizes, int n_in,
                              void* d_out, int out_size, void* d_ws, size_t ws_size,
                              hipStream_t stream) {
    const float* x  = (const float*)d_in[0];
    const float* W1 = (const float*)d_in[1];
    const float* b1 = (const float*)d_in[2];
    const float* W2 = (const float*)d_in[3];
    const float* b2 = (const float*)d_in[4];
    float* out = (float*)d_out;

    char* ws = (char*)d_ws;
    float* e       = (float*)ws;  ws += (size_t)B_ * T_ * 4;
    float* beta    = (float*)ws;  ws += (size_t)B_ * T_ * 4;
    float* partial = (float*)ws;  ws += (size_t)B_ * NC * D_ * 4;
    ushort* Whi    = (ushort*)ws; ws += (size_t)H_ * D_ * 2;
    ushort* Wlo    = (ushort*)ws; ws += (size_t)H_ * D_ * 2;
    int* counts    = (int*)ws;    ws += 128;
    int* list      = (int*)ws;

    k_w1t<<<dim3(D_ / 32, H_ / 32), 256, 0, stream>>>(W1, Whi, Wlo);
    k_e_mfma<<<(B_ * T_) / BM, 512, 0, stream>>>(x, Whi, Wlo, b1, W2, b2, e);
    k_thresh<1><<<B_, 256, 0, stream>>>(e, nullptr, counts, list);
    k_refine<<<dim3(MAXBAND, B_), 256, 0, stream>>>(x, W1, b1, W2, b2, counts, list, e);
    k_thresh<0><<<B_, 256, 0, stream>>>(e, beta, counts, list);
    k_pv<<<dim3(NC, B_), 256, 0, stream>>>(x, beta, partial);
    k_red<<<B_, 256, 0, stream>>>(partial, out);
}